// Round 4
// baseline (536.579 us; speedup 1.0000x reference)
//
#include <hip/hip_runtime.h>
#include <hip/hip_bf16.h>
#include <cstdint>
#include <cstddef>

typedef __attribute__((ext_vector_type(8))) short short8;
typedef __attribute__((ext_vector_type(4))) float floatx4;

#define MFMA_BF16(a,b,c) __builtin_amdgcn_mfma_f32_16x16x32_bf16((a),(b),(c),0,0,0)

__device__ __forceinline__ float bf2f(short s) {
    return __uint_as_float(((unsigned int)(unsigned short)s) << 16);
}
__device__ __forceinline__ unsigned short f2bf(float f) {
    unsigned int u = __float_as_uint(f);
    u += 0x7FFFu + ((u >> 16) & 1u);
    return (unsigned short)(u >> 16);
}
__device__ __forceinline__ int bucketd(int d) {
    if (d < 0) d = 0;
    if (d <= 4) return d;
    int b = 34 - __clz(d);          // floor(log2(d)) + 3
    return b > 9 ? 9 : b;
}

// ---------------- prep: all precomputes + weight transposes in ONE kernel ----------------
__global__ __launch_bounds__(256) void k_prep(
    const float* __restrict__ Wg, const float* __restrict__ Wl, const float* __restrict__ Wr,
    const float* __restrict__ Wp, const float* __restrict__ Wpr,
    const float* __restrict__ span_vecs, const float* __restrict__ span_scores,
    const float* __restrict__ W1g, const float* __restrict__ Edist,
    const float* __restrict__ Wd, const float* __restrict__ bd,
    const float* __restrict__ b1, const float* __restrict__ Wo,
    const float* __restrict__ bl, const float* __restrict__ br, const float* __restrict__ bp,
    const float* __restrict__ bpr,
    unsigned short* __restrict__ WgT, unsigned short* __restrict__ WprojT,
    unsigned short* __restrict__ updT, unsigned short* __restrict__ ubf0,
    float* __restrict__ updatef, float* __restrict__ ss0,
    unsigned short* __restrict__ W1T, unsigned short* __restrict__ Pb,
    float* __restrict__ b1p, float* __restrict__ wop, float* __restrict__ bproj)
{
    __shared__ float tile[32][33];
    int b = blockIdx.x, tid = threadIdx.x;
    if (b < 3040) {
        const float* in; unsigned short* out; int R, C, ldo, rb, cb;
        if (b < 2048)      { in = Wg; out = WgT; R = 2048; C = 1024; ldo = 2048; rb = (b & 63) * 32; cb = (b >> 6) * 32; }
        else if (b < 2208) { int t = b - 2048; in = Wl; out = WprojT;            R = 1024; C = 150; ldo = 1024; rb = (t & 31) * 32; cb = (t >> 5) * 32; }
        else if (b < 2368) { int t = b - 2208; in = Wr; out = WprojT + 192*1024; R = 1024; C = 150; ldo = 1024; rb = (t & 31) * 32; cb = (t >> 5) * 32; }
        else if (b < 2528) { int t = b - 2368; in = Wp; out = WprojT + 384*1024; R = 1024; C = 150; ldo = 1024; rb = (t & 31) * 32; cb = (t >> 5) * 32; }
        else               { int t = b - 2528; in = span_vecs; out = updT;       R = 512;  C = 1024; ldo = 512;  rb = (t & 15) * 32; cb = (t >> 4) * 32; }
        int tx = tid & 31, ty = tid >> 5;
#pragma unroll
        for (int k = 0; k < 4; ++k) {
            int r = rb + ty + k*8, c = cb + tx;
            if (r < R && c < C) tile[ty + k*8][tx] = in[(size_t)r*C + c];
        }
        __syncthreads();
#pragma unroll
        for (int k = 0; k < 4; ++k) {
            int c = cb + ty + k*8, r = rb + tx;
            if (r < R && c < C) out[(size_t)c*ldo + r] = f2bf(tile[tx][ty + k*8]);
        }
        return;
    }
    int g = (b - 3040) * 256 + tid;
    const int gsz = 512 * 256;
    for (int i = g; i < 512*1024; i += gsz) {
        float v = span_vecs[i];
        updatef[i] = v;
        ubf0[(i >> 10)*2048 + (i & 1023)] = f2bf(v);
    }
    for (int i = g; i < 512; i += gsz) ss0[i] = span_scores[i];
    for (int i = g; i < 160*168; i += gsz) {
        int n = i / 168, k = i % 168;
        W1T[i] = f2bf((n < 150 && k < 150) ? W1g[k*150 + n] : 0.f);
    }
    for (int i = g; i < 10*168; i += gsz) {
        int bk = i / 168, h = i % 168;
        float v = 0.f;
        if (h < 150) {
            v = bd[h];
            for (int e = 0; e < 20; ++e) v += Edist[bk*20 + e] * Wd[e*150 + h];
        }
        Pb[i] = f2bf(v);
    }
    for (int i = g; i < 160; i += gsz) {
        b1p[i] = (i < 150) ? b1[i] : 0.f;
        wop[i] = (i < 150) ? Wo[i] : 0.f;
    }
    for (int i = g; i < 640; i += gsz) {
        float v = 0.f;
        if (i < 150) v = bl[i];
        else if (i >= 192 && i < 342) v = br[i - 192];
        else if (i >= 384 && i < 534) v = bp[i - 384];
        else if (i == 576) v = bpr[0];
        bproj[i] = v;
    }
    for (int i = g; i < 42*1024; i += gsz) { WprojT[150*1024 + i] = 0; WprojT[342*1024 + i] = 0; WprojT[534*1024 + i] = 0; }
    for (int i = g; i < 1024; i += gsz) WprojT[576*1024 + i] = f2bf(Wpr[i]);
    for (int i = g; i < 63*1024; i += gsz) WprojT[577*1024 + i] = 0;
}

// ---------------- 32x64-tile bf16 MFMA GEMM, depth-2 register pipeline ----------------
// C[m][n] = sum_k A[m][k] * BT[n][k];  grid (M/32, N/64), 256 threads
// mode 0: Cb = bf16(acc+bias); if n==576 also ss1[m]   (projections+pruner)
// mode 1: Cf = acc (ld 1024); Cb = bf16(acc)           (ctxt)
// mode 2: g = sigmoid(acc+bias); nu = g*uf+(1-g)*cf; -> uout, Cb, updT (gate)
__global__ __launch_bounds__(256, 4) void k_gemm(
    const unsigned short* __restrict__ A, int lda,
    const unsigned short* __restrict__ BT, int ldb,
    int K, const float* __restrict__ bias,
    float* __restrict__ Cf,
    unsigned short* __restrict__ Cb, int ldcb,
    const float* __restrict__ uf, const float* __restrict__ cf,
    float* __restrict__ uout, unsigned short* __restrict__ updTout,
    float* __restrict__ ss1, int mode)
{
    __shared__ __align__(16) unsigned short As[32*72];
    __shared__ __align__(16) unsigned short Bs[64*72];
    int tid = threadIdx.x;
    int lane = tid & 63, w = tid >> 6;
    int wy = w >> 1, wx = w & 1;
    int ln15 = lane & 15, kg = lane >> 4;
    int m0 = blockIdx.x * 32, n0 = blockIdx.y * 64;
    int rA = tid >> 3, c8 = (tid & 7) * 8;
    const unsigned short* pA  = A  + (size_t)(m0 + rA)*lda + c8;
    const unsigned short* pB0 = BT + (size_t)(n0 + rA)*ldb + c8;
    const unsigned short* pB1 = pB0 + (size_t)32*ldb;
    int nk = K >> 6;
    uint4 ra[2], rb0[2], rb1[2];
    ra[0]  = *(const uint4*)pA;        ra[1]  = *(const uint4*)(pA + 64);
    rb0[0] = *(const uint4*)pB0;       rb0[1] = *(const uint4*)(pB0 + 64);
    rb1[0] = *(const uint4*)pB1;       rb1[1] = *(const uint4*)(pB1 + 64);
    floatx4 acc[2] = {};
    for (int k = 0; k < nk; ++k) {
        int cur = k & 1;
        __syncthreads();
        *(uint4*)(&As[rA*72 + c8])        = ra[cur];
        *(uint4*)(&Bs[rA*72 + c8])        = rb0[cur];
        *(uint4*)(&Bs[(rA + 32)*72 + c8]) = rb1[cur];
        int kn = (k + 2) << 6;
        if (kn < K) {
            ra[cur]  = *(const uint4*)(pA + kn);
            rb0[cur] = *(const uint4*)(pB0 + kn);
            rb1[cur] = *(const uint4*)(pB1 + kn);
        }
        __syncthreads();
#pragma unroll
        for (int ks = 0; ks < 2; ++ks) {
            int ko = ks*32 + kg*8;
            short8 a  = *(const short8*)(&As[(wy*16 + ln15)*72 + ko]);
            short8 b0 = *(const short8*)(&Bs[(wx*32 + ln15)*72 + ko]);
            short8 b1 = *(const short8*)(&Bs[(wx*32 + 16 + ln15)*72 + ko]);
            acc[0] = MFMA_BF16(a, b0, acc[0]);
            acc[1] = MFMA_BF16(a, b1, acc[1]);
        }
    }
#pragma unroll
    for (int nt = 0; nt < 2; ++nt) {
        int n  = n0 + wx*32 + nt*16 + ln15;
        int mb = m0 + wy*16 + kg*4;
        if (mode == 0) {
            float b_ = bias[n];
#pragma unroll
            for (int rg = 0; rg < 4; ++rg) {
                float v = acc[nt][rg] + b_;
                Cb[(size_t)(mb + rg)*ldcb + n] = f2bf(v);
                if (n == 576) ss1[mb + rg] = v;
            }
        } else if (mode == 1) {
#pragma unroll
            for (int rg = 0; rg < 4; ++rg) {
                float v = acc[nt][rg];
                Cf[(size_t)(mb + rg)*1024 + n] = v;
                Cb[(size_t)(mb + rg)*ldcb + n] = f2bf(v);
            }
        } else {
            float b_ = bias[n];
            ushort4 tv; unsigned short* tvp = &tv.x;
#pragma unroll
            for (int rg = 0; rg < 4; ++rg) {
                float v = acc[nt][rg] + b_;
                float gg = 1.f / (1.f + __expf(-v));
                size_t off = (size_t)(mb + rg)*1024 + n;
                float nu = gg*uf[off] + (1.f - gg)*cf[off];
                uout[off] = nu;
                unsigned short nb = f2bf(nu);
                Cb[(size_t)(mb + rg)*ldcb + n] = nb;
                tvp[rg] = nb;
            }
            *(ushort4*)(updTout + (size_t)n*512 + mb) = tv;
        }
    }
}

// ---------------- row softmax (masked j<=i) -> bf16 probs ----------------
__global__ __launch_bounds__(256) void k_softmax(const float* __restrict__ scores,
                                                 unsigned short* __restrict__ probsb)
{
    int i = blockIdx.x;
    int tid = threadIdx.x;
    int lane = tid & 63, w = tid >> 6;
    __shared__ float red[8];
    int j0 = tid, j1 = tid + 256;
    bool v0 = (j0 <= i), v1 = (j1 <= i);
    float x0 = v0 ? scores[(size_t)i*512 + j0] : -1e30f;
    float x1 = v1 ? scores[(size_t)i*512 + j1] : -1e30f;
    float mx = fmaxf(x0, x1);
    for (int off = 32; off; off >>= 1) mx = fmaxf(mx, __shfl_xor(mx, off));
    if (lane == 0) red[w] = mx;
    __syncthreads();
    mx = fmaxf(fmaxf(red[0], red[1]), fmaxf(red[2], red[3]));
    float p0 = v0 ? __expf(x0 - mx) : 0.f;
    float p1 = v1 ? __expf(x1 - mx) : 0.f;
    float sm = p0 + p1;
    for (int off = 32; off; off >>= 1) sm += __shfl_xor(sm, off);
    if (lane == 0) red[4 + w] = sm;
    __syncthreads();
    float inv = 1.f / (red[4] + red[5] + red[6] + red[7]);
    probsb[(size_t)i*512 + j0] = f2bf(p0 * inv);
    probsb[(size_t)i*512 + j1] = f2bf(p1 * inv);
}

// ---------------- pair kernel: W1T slice LDS-staged (double-buffered, 1 barrier/kb) ----------
__global__ __launch_bounds__(512, 2) void k_pair(
    const unsigned short* __restrict__ lrsb,   // [512][640] bf16: l|pad|r|pad|s|pad|ss|pad
    const unsigned short* __restrict__ Pb,     // [10][168]
    const unsigned short* __restrict__ W1Tg,   // [160][168]
    const float* __restrict__ b1p, const float* __restrict__ wop,
    const float* __restrict__ bo,
    const float* __restrict__ ssbuf,
    const int* __restrict__ beginp, const int* __restrict__ endp,
    float* __restrict__ scoresOut)
{
    __shared__ __align__(16) unsigned short smR[74*168];    // l_i s_i r_j s_j P
    __shared__ __align__(16) unsigned short smB[2][160*36]; // W1T k-slice, dbuf
    int tid = threadIdx.x;
    int i0 = blockIdx.x * 16, j0 = blockIdx.y * 16;
    for (int c = tid; c < 74*21; c += 512) {
        int row = c / 21, c8 = (c % 21) * 8;
        const unsigned short* src;
        if (row < 16)      src = lrsb + (size_t)(i0 + row)*640 + c8;
        else if (row < 32) src = lrsb + (size_t)(i0 + row - 16)*640 + 384 + c8;
        else if (row < 48) src = lrsb + (size_t)(j0 + row - 32)*640 + 192 + c8;
        else if (row < 64) src = lrsb + (size_t)(j0 + row - 48)*640 + 384 + c8;
        else               src = Pb + (size_t)(row - 64)*168 + c8;
        *(uint4*)(&smR[row*168 + c8]) = *(const uint4*)src;
    }
    int lane = tid & 63, w = tid >> 6;
    int ln15 = lane & 15, kg = lane >> 4;
    int iw = i0 + 2*w;
    int ej = endp[j0 + ln15];
    int da = bucketd(beginp[iw] - ej);
    int db = bucketd(beginp[iw + 1] - ej);
    // W1T slice staging: rows 0..127 by all threads, rows 128..159 by tid<128
    int rW = tid >> 2, cW = (tid & 3) * 8;
    int rW2 = 128 + rW;
    bool has2 = (tid < 128);
    uint4 w0 = *(const uint4*)(W1Tg + (size_t)rW*168 + cW);
    uint4 w1 = has2 ? *(const uint4*)(W1Tg + (size_t)rW2*168 + cW) : make_uint4(0,0,0,0);
    floatx4 acc[2][10] = {};
    for (int kb = 0; kb < 5; ++kb) {
        int cur = kb & 1;
        *(uint4*)(&smB[cur][rW*36 + cW]) = w0;
        if (has2) *(uint4*)(&smB[cur][rW2*36 + cW]) = w1;
        if (kb < 4) {
            int kf = (kb + 1)*32;
            w0 = *(const uint4*)(W1Tg + (size_t)rW*168 + kf + cW);
            if (has2) w1 = *(const uint4*)(W1Tg + (size_t)rW2*168 + kf + cW);
        }
        __syncthreads();
        int ko = kb*32 + kg*8;
        short8 rv  = *(const short8*)(&smR[(32 + ln15)*168 + ko]);
        short8 sjv = *(const short8*)(&smR[(48 + ln15)*168 + ko]);
        short8 hf[2];
#pragma unroll
        for (int mt = 0; mt < 2; ++mt) {
            int ri = 2*w + mt;
            short8 lv  = *(const short8*)(&smR[ri*168 + ko]);
            short8 siv = *(const short8*)(&smR[(16 + ri)*168 + ko]);
            int d = mt ? db : da;
            short8 pv  = *(const short8*)(&smR[(64 + d)*168 + ko]);
#pragma unroll
            for (int t = 0; t < 8; ++t) {
                float h = bf2f(lv[t]) + bf2f(rv[t]) + bf2f(siv[t]) * bf2f(sjv[t]) + bf2f(pv[t]);
                h = fmaxf(h, 0.f);
                hf[mt][t] = (short)f2bf(h);
            }
        }
#pragma unroll
        for (int nt = 0; nt < 10; ++nt) {
            short8 bv = *(const short8*)(&smB[cur][(nt*16 + ln15)*36 + kg*8]);
            acc[0][nt] = MFMA_BF16(hf[0], bv, acc[0][nt]);
            acc[1][nt] = MFMA_BF16(hf[1], bv, acc[1][nt]);
        }
    }
    float part[2][4] = {};
#pragma unroll
    for (int nt = 0; nt < 10; ++nt) {
        int n = nt*16 + ln15;
        float b1v = b1p[n], wv = wop[n];
#pragma unroll
        for (int mt = 0; mt < 2; ++mt)
#pragma unroll
            for (int rg = 0; rg < 4; ++rg)
                part[mt][rg] += fmaxf(acc[mt][nt][rg] + b1v, 0.f) * wv;
    }
    float bo0 = bo[0];
#pragma unroll
    for (int mt = 0; mt < 2; ++mt) {
#pragma unroll
        for (int rg = 0; rg < 4; ++rg) {
            float p = part[mt][rg];
            p += __shfl_xor(p, 1); p += __shfl_xor(p, 2);
            p += __shfl_xor(p, 4); p += __shfl_xor(p, 8);
            part[mt][rg] = p;
        }
        if (ln15 == 0) {
            int i = iw + mt;
            float ssi = ssbuf[i];
            int jb = j0 + kg*4;
            float r0 = part[mt][0] + bo0 + ssi + ssbuf[jb + 0]; if (i == jb + 0) r0 = 0.f;
            float r1 = part[mt][1] + bo0 + ssi + ssbuf[jb + 1]; if (i == jb + 1) r1 = 0.f;
            float r2 = part[mt][2] + bo0 + ssi + ssbuf[jb + 2]; if (i == jb + 2) r2 = 0.f;
            float r3 = part[mt][3] + bo0 + ssi + ssbuf[jb + 3]; if (i == jb + 3) r3 = 0.f;
            float4 vv; vv.x = r0; vv.y = r1; vv.z = r2; vv.w = r3;
            *(float4*)(scoresOut + (size_t)i*512 + jb) = vv;
        }
    }
}

// ---------------- finalize: copy + overwrite merged (binary search over sorted prune) --------
__global__ __launch_bounds__(256) void k_final(const float* __restrict__ allv,
                                               const int* __restrict__ prune,
                                               const int* __restrict__ lengths,
                                               const float* __restrict__ updatef,
                                               float* __restrict__ out)
{
    int row = blockIdx.x;
    if (row < 30720) {
        int len = lengths[0];
        if (len > 512) len = 512;
        int lo = 0, hi = len;
        while (lo < hi) { int mid = (lo + hi) >> 1; if (prune[mid] < row) lo = mid + 1; else hi = mid; }
        bool found = (lo < len) && (prune[lo] == row);
        const float4* src = found ? (const float4*)(updatef + (size_t)lo*1024)
                                  : (const float4*)(allv + (size_t)row*1024);
        ((float4*)(out + (size_t)row*1024))[threadIdx.x] = src[threadIdx.x];
    } else {
        int k = row - 30720;
        ((float4*)(out + (size_t)row*1024))[threadIdx.x] =
            ((const float4*)(updatef + (size_t)k*1024))[threadIdx.x];
    }
}

// ---------------- host ----------------
extern "C" void kernel_launch(void* const* d_in, const int* in_sizes, int n_in,
                              void* d_out, int out_size, void* d_ws, size_t ws_size,
                              hipStream_t stream) {
    const float* all_span    = (const float*)d_in[0];
    const float* span_vecs   = (const float*)d_in[1];
    const float* span_scores = (const float*)d_in[2];
    const int*   beginp      = (const int*)d_in[4];
    const int*   endp        = (const int*)d_in[5];
    const int*   prune       = (const int*)d_in[6];
    const int*   lengths     = (const int*)d_in[7];
    const float* Wl = (const float*)d_in[8];  const float* bl = (const float*)d_in[9];
    const float* Wr = (const float*)d_in[10]; const float* br = (const float*)d_in[11];
    const float* Wp = (const float*)d_in[12]; const float* bp = (const float*)d_in[13];
    const float* Edist = (const float*)d_in[14];
    const float* Wd = (const float*)d_in[15]; const float* bd = (const float*)d_in[16];
    const float* W1 = (const float*)d_in[17]; const float* b1 = (const float*)d_in[18];
    const float* Wo = (const float*)d_in[19]; const float* bo = (const float*)d_in[20];
    const float* Wg = (const float*)d_in[21]; const float* bg = (const float*)d_in[22];
    const float* Wpr = (const float*)d_in[23]; const float* bpr = (const float*)d_in[24];

    char* wsb = (char*)d_ws;
    size_t o = 0;
    auto nxt = [&](size_t b) { size_t r = o; o += (b + 255) & ~(size_t)255; return r; };
    float* updatef  = (float*)(wsb + nxt(512*1024*4));
    float* ctxtf    = (float*)(wsb + nxt(512*1024*4));
    float* scoresws = (float*)(wsb + nxt(512*512*4));
    float* ss0      = (float*)(wsb + nxt(512*4));
    float* ss1      = (float*)(wsb + nxt(512*4));
    float* bproj    = (float*)(wsb + nxt(640*4));
    float* b1p      = (float*)(wsb + nxt(160*4));
    float* wop      = (float*)(wsb + nxt(160*4));
    unsigned short* ubf0    = (unsigned short*)(wsb + nxt(512*2048*2));
    unsigned short* ubf1    = (unsigned short*)(wsb + nxt(512*2048*2));
    unsigned short* updT    = (unsigned short*)(wsb + nxt(1024*512*2));
    unsigned short* probsb  = (unsigned short*)(wsb + nxt(512*512*2));
    unsigned short* lrsb    = (unsigned short*)(wsb + nxt(512*640*2));
    unsigned short* WgT     = (unsigned short*)(wsb + nxt(1024*2048*2));
    unsigned short* WprojT  = (unsigned short*)(wsb + nxt(640*1024*2));
    unsigned short* W1T     = (unsigned short*)(wsb + nxt(160*168*2));
    unsigned short* Pb      = (unsigned short*)(wsb + nxt(10*168*2));

    float* outp = (float*)d_out;
    float* out_scores = outp + 31457280 + 524288;

    k_prep<<<3552, 256, 0, stream>>>(Wg, Wl, Wr, Wp, Wpr, span_vecs, span_scores,
                                     W1, Edist, Wd, bd, b1, Wo, bl, br, bp, bpr,
                                     WgT, WprojT, updT, ubf0, updatef, ss0,
                                     W1T, Pb, b1p, wop, bproj);

    // call 0: projections (+fused pruner col, unused), pair with span_scores
    k_gemm<<<dim3(16, 10), 256, 0, stream>>>(ubf0, 2048, WprojT, 1024, 1024, bproj,
                                             nullptr, lrsb, 640,
                                             nullptr, nullptr, nullptr, nullptr, ss1, 0);
    k_pair<<<dim3(32, 32), 512, 0, stream>>>(lrsb, Pb, W1T, b1p, wop, bo, ss0, beginp, endp, scoresws);

    unsigned short* ucur = ubf0;
    unsigned short* unxt = ubf1;
    for (int it = 0; it < 2; ++it) {
        k_softmax<<<512, 256, 0, stream>>>(scoresws, probsb);
        // ctxt = probs @ update
        k_gemm<<<dim3(16, 16), 256, 0, stream>>>(probsb, 512, updT, 512, 512, nullptr,
                                                 ctxtf, ucur + 1024, 2048,
                                                 nullptr, nullptr, nullptr, nullptr, nullptr, 1);
        // gate: writes updatef (fp32), unxt (bf16 rows), updT (bf16 transposed)
        k_gemm<<<dim3(16, 16), 256, 0, stream>>>(ucur, 2048, WgT, 2048, 2048, bg,
                                                 nullptr, unxt, 2048,
                                                 updatef, ctxtf, updatef, updT, nullptr, 2);
        // projections of new update (+fused pruner -> ss1)
        k_gemm<<<dim3(16, 10), 256, 0, stream>>>(unxt, 2048, WprojT, 1024, 1024, bproj,
                                                 nullptr, lrsb, 640,
                                                 nullptr, nullptr, nullptr, nullptr, ss1, 0);
        float* sdst = (it == 1) ? out_scores : scoresws;
        k_pair<<<dim3(32, 32), 512, 0, stream>>>(lrsb, Pb, W1T, b1p, wop, bo, ss1, beginp, endp, sdst);
        unsigned short* t = ucur; ucur = unxt; unxt = t;
    }

    k_final<<<31232, 256, 0, stream>>>(all_span, prune, lengths, updatef, outp);
}